// Round 6
// baseline (137.341 us; speedup 1.0000x reference)
//
#include <hip/hip_runtime.h>
#include <hip/hip_bf16.h>
#include <math.h>

#define KOBJ 256
#define B1   64               // partial-accumulator blocks
#define QMIN 0.5f
#define BETA_CLIP_C (1.0f - 1e-5f)

typedef unsigned long long u64;

// accum layout (floats): [0]=s0 sum, [1]=n_valid, [2]=cnt sum, [3]=noise sum, [4]=counter(int bits)

// ---------------- Kernel A: per-point compute + LDS accumulation + packed pts4
__global__ __launch_bounds__(256) void partials(
    const float*  __restrict__ pred_beta,
    const float2* __restrict__ pred_ccoords,
    const float*  __restrict__ pred_energy,
    const float2* __restrict__ pred_pos,
    const float*  __restrict__ pred_time,
    const float2* __restrict__ pred_id2,
    const float*  __restrict__ t_energy,
    const float2* __restrict__ t_pos,
    const float*  __restrict__ t_time,
    const int*    __restrict__ t_idx,
    float4* __restrict__ pts4,      // [npad] (x, y, q, idx-bits)
    u64*    __restrict__ pkb,       // [B1][K]  b-major (heavy's coalesced merge)
    u64*    __restrict__ pkk,       // [K][B1]  k-major (final's coalesced read)
    float*  __restrict__ cntk,      // [K][B1]
    float*  __restrict__ denk,      // [K][B1]
    float4* __restrict__ numk,      // [K][B1]
    float*  __restrict__ noise_part,// [B1]
    float*  __restrict__ accum,     // [8]
    int n, int npad)
{
    __shared__ u64   spk[KOBJ];
    __shared__ float scnt[KOBJ];
    __shared__ float sden[KOBJ], sn0[KOBJ], sn1[KOBJ], sn2[KOBJ], sn3[KOBJ];
    __shared__ float snoise[256];
    int t = threadIdx.x;
    int b = blockIdx.x;
    spk[t] = 0; scnt[t] = 0.f; sden[t] = 0.f;
    sn0[t] = 0.f; sn1[t] = 0.f; sn2[t] = 0.f; sn3[t] = 0.f;
    if (b == 0 && t < 8) accum[t] = 0.0f;   // zero finish-accumulators + counter
    __syncthreads();

    float noise = 0.0f;
    for (int i = b * 256 + t; i < npad; i += B1 * 256) {
        if (i < n) {
            int tid = t_idx[i];
            float braw = pred_beta[i];
            float beta = fminf(fmaxf(braw, 0.0f), BETA_CLIP_C);
            float at = atanhf(beta);
            float2 cc = pred_ccoords[i];
            pts4[i] = make_float4(cc.x, cc.y, at * at + QMIN, __int_as_float(tid));
            if (tid >= 0) {
                atomicAdd(&scnt[tid], 1.0f);
                u64 key = ((u64)__float_as_uint(beta) << 32) |
                          (u64)(0x7FFFFFFFu - (unsigned)i);   // max beta, tie -> lowest i
                atomicMax(&spk[tid], key);
                float te = t_energy[i];
                float ew = (te > 10.0f) ? 1.0f : fmaxf(0.0f, (te - 0.5f) / 9.5f);
                float de = te - pred_energy[i];
                float el = de * de / (te + 1.0f);
                float2 tp = t_pos[i];
                float2 pp = pred_pos[i];
                float dpx = tp.x - pp.x, dpy = tp.y - pp.y;
                float pl = (dpx * dpx + dpy * dpy) * 0.01f;
                float dt = t_time[i] - pred_time[i];
                float tl = dt * dt;
                float2 id0 = pred_id2[3 * i];
                float2 id1 = pred_id2[3 * i + 1];
                float2 id2 = pred_id2[3 * i + 2];
                float cs = id0.x * id0.x + id0.y * id0.y + id1.x * id1.x +
                           id1.y * id1.y + id2.x * id2.x + id2.y * id2.y;
                cs *= (1e-8f / 6.0f);
                float mask = (braw < 0.1f) ? 0.0f : 1.0f;
                float w = mask * ew * beta;
                atomicAdd(&sden[tid], beta);
                atomicAdd(&sn0[tid], el * w);
                atomicAdd(&sn1[tid], pl * w);
                atomicAdd(&sn2[tid], tl * w);
                atomicAdd(&sn3[tid], cs * w);
            } else {
                noise += beta;
            }
        } else {
            pts4[i] = make_float4(0.f, 0.f, 0.f, __int_as_float(-2)); // q=0 => inert
        }
    }
    __syncthreads();
    pkb[b * KOBJ + t] = spk[t];                 // coalesced
    pkk[t * B1 + b]   = spk[t];                 // scattered (small)
    cntk[t * B1 + b]  = scnt[t];
    denk[t * B1 + b]  = sden[t];
    numk[t * B1 + b]  = make_float4(sn0[t], sn1[t], sn2[t], sn3[t]);
    snoise[t] = noise;
    __syncthreads();
    for (int s = 128; s > 0; s >>= 1) {
        if (t < s) snoise[t] += snoise[t + s];
        __syncthreads();
    }
    if (t == 0) noise_part[b] = snoise[0];
}

// ---------------- Kernel B: merge-in-prologue + N x K hinge/attraction
__global__ __launch_bounds__(256) void heavy(
    const float2* __restrict__ pred_ccoords,
    const u64*    __restrict__ pkb,
    const float4* __restrict__ pts4,
    float* __restrict__ rep_part,   // [K][hstr]
    float* __restrict__ att_part,   // [K][hstr]
    int hstr)
{
    int t = threadIdx.x;
    // per-k alpha merge: 64 coalesced u64 loads (L2-hot, shared by all blocks)
    u64 pk = 0;
    #pragma unroll 8
    for (int b = 0; b < B1; ++b) {
        u64 p = pkb[b * KOBJ + t];
        pk = (p > pk) ? p : pk;
    }
    float xk = 0.f, yk = 0.f;
    if (pk != 0) {
        unsigned a = 0x7FFFFFFFu - (unsigned)(pk & 0xFFFFFFFFull);
        float2 cc = pred_ccoords[a];
        xk = cc.x; yk = cc.y;
    }
    const float4* __restrict__ chunk = pts4 + (size_t)blockIdx.x * 256;
    float rep = 0.f, att = 0.f;
    #pragma unroll 8
    for (int j = 0; j < 256; ++j) {
        float4 s = chunk[j];                  // wave-uniform address -> broadcast
        float dx = s.x - xk, dy = s.y - yk;
        float d2 = fmaf(dx, dx, dy * dy);
        float r = __builtin_amdgcn_sqrtf(d2 + 1e-6f);
        float h = fmaxf(0.0f, 1.0f - r);
        bool own = (__float_as_int(s.w) == t);
        rep = fmaf(own ? 0.0f : h,  s.z, rep);
        att = fmaf(own ? d2 : 0.0f, s.z, att);
    }
    int o = t * hstr + blockIdx.x;
    rep_part[o] = rep;
    att_part[o] = att;
}

// ---------------- Kernel C: per-object finish + last-block scalar write
__global__ __launch_bounds__(256) void final_k(
    const u64*    __restrict__ pkk,
    const float*  __restrict__ cntk,
    const float*  __restrict__ denk,
    const float4* __restrict__ numk,
    const float*  __restrict__ rep_part,
    const float*  __restrict__ att_part,
    const float*  __restrict__ noise_part,
    float* __restrict__ accum,
    float* __restrict__ out,
    int n, int nbh, int hstr)
{
    __shared__ float srep[256], satt[256], scnt[256], sden[256], snum[256], snoi[256];
    __shared__ u64 spk[256];
    int k = blockIdx.x;
    int t = threadIdx.x;
    float rep = 0.f, att = 0.f;
    int o = k * hstr + t;
    if (t < nbh)        { rep += rep_part[o];        att += att_part[o]; }
    if (t + 256 < nbh)  { rep += rep_part[o + 256];  att += att_part[o + 256]; }
    u64 pk = 0; float cnt = 0.f, den = 0.f, ns = 0.f, noi = 0.f;
    if (t < B1) {
        int p = k * B1 + t;
        pk = pkk[p];
        cnt = cntk[p];
        den = denk[p];
        float4 v = numk[p];
        ns = v.x + v.y + v.z + v.w;
        if (k == 0) noi = noise_part[t];
    }
    srep[t] = rep; satt[t] = att; scnt[t] = cnt; sden[t] = den;
    snum[t] = ns; snoi[t] = noi; spk[t] = pk;
    __syncthreads();
    for (int s = 128; s > 0; s >>= 1) {
        if (t < s) {
            srep[t] += srep[t + s]; satt[t] += satt[t + s];
            scnt[t] += scnt[t + s]; sden[t] += sden[t + s];
            snum[t] += snum[t + s]; snoi[t] += snoi[t + s];
            u64 p = spk[t + s]; if (p > spk[t]) spk[t] = p;
        }
        __syncthreads();
    }
    if (t == 0) {
        u64 p = spk[0];
        float cs = scnt[0];
        float s0 = 0.f, valid = 0.f;
        if (p != 0) {
            valid = 1.f;
            float ba = __uint_as_float((unsigned)(p >> 32));
            float at = atanhf(ba);
            float qa = at * at + QMIN;
            float lb = 1.0f - ba;
            float pay = snum[0] / fmaxf(sden[0], 1e-6f);
            float vatt = satt[0] * qa / fmaxf(cs, 1.0f);
            float vrep = srep[0] * qa / fmaxf((float)n - cs, 1.0f);
            s0 = vatt + vrep + lb + pay;
        }
        atomicAdd(&accum[0], s0);
        atomicAdd(&accum[1], valid);
        atomicAdd(&accum[2], cs);
        atomicAdd(&accum[3], snoi[0]);      // zero for all blocks except 0
        __threadfence();
        int prev = atomicAdd((int*)&accum[4], 1);
        if (prev == KOBJ - 1) {             // last block: everything visible
            __threadfence();
            volatile float* va = accum;
            float ssum = va[0], nvs = va[1], csum = va[2], nsum = va[3];
            float nv = fmaxf(nvs, 1.0f);
            float nnoise = fmaxf((float)n - csum, 1.0f);
            out[0] = ssum / nv + nsum / nnoise;
        }
    }
}

extern "C" void kernel_launch(void* const* d_in, const int* in_sizes, int n_in,
                              void* d_out, int out_size, void* d_ws, size_t ws_size,
                              hipStream_t stream) {
    const float*  pred_beta    = (const float*)d_in[0];
    const float2* pred_ccoords = (const float2*)d_in[1];
    const float*  pred_energy  = (const float*)d_in[2];
    const float2* pred_pos     = (const float2*)d_in[3];
    const float*  pred_time    = (const float*)d_in[4];
    const float2* pred_id2     = (const float2*)d_in[5];
    const float*  t_energy     = (const float*)d_in[6];
    const float2* t_pos        = (const float2*)d_in[7];
    const float*  t_time       = (const float*)d_in[8];
    const int*    t_idx        = (const int*)d_in[10];
    int n = in_sizes[0];
    int nbh = (n + 255) / 256;          // 391 for n=100000
    int npad = nbh * 256;
    int hstr = (nbh + 8) & ~7;          // padded row stride (8-aligned), >= nbh+1

    // workspace carve (16B-aligned)
    char* base = (char*)d_ws;
    size_t off = 0;
    float4* pts4  = (float4*)(base + off); off += (size_t)npad * 16;            // 1.6 MB
    u64*    pkb   = (u64*)   (base + off); off += (size_t)B1 * KOBJ * 8;        // 128 KB
    u64*    pkk   = (u64*)   (base + off); off += (size_t)KOBJ * B1 * 8;        // 128 KB
    float*  cntk  = (float*) (base + off); off += (size_t)KOBJ * B1 * 4;        // 64 KB
    float*  denk  = (float*) (base + off); off += (size_t)KOBJ * B1 * 4;        // 64 KB
    float4* numk  = (float4*)(base + off); off += (size_t)KOBJ * B1 * 16;       // 256 KB
    float*  noise_part = (float*)(base + off); off += 256 * 4;
    float*  accum = (float*) (base + off); off += 64;
    float*  rep_part = (float*)(base + off); off += (size_t)KOBJ * hstr * 4;    // ~400 KB
    float*  att_part = (float*)(base + off); off += (size_t)KOBJ * hstr * 4;

    partials<<<B1, 256, 0, stream>>>(pred_beta, pred_ccoords, pred_energy, pred_pos,
                                     pred_time, pred_id2, t_energy, t_pos, t_time, t_idx,
                                     pts4, pkb, pkk, cntk, denk, numk, noise_part, accum,
                                     n, npad);
    heavy<<<nbh, 256, 0, stream>>>(pred_ccoords, pkb, pts4, rep_part, att_part, hstr);
    final_k<<<KOBJ, 256, 0, stream>>>(pkk, cntk, denk, numk, rep_part, att_part,
                                      noise_part, accum, (float*)d_out, n, nbh, hstr);
}

// Round 7
// 110.668 us; speedup vs baseline: 1.2410x; 1.2410x over previous
//
#include <hip/hip_runtime.h>
#include <hip/hip_bf16.h>
#include <math.h>

#define KOBJ 256
#define B1   256              // partial-accumulator blocks (R5-proven)
#define QMIN 0.5f
#define BETA_CLIP_C (1.0f - 1e-5f)

typedef unsigned long long u64;

// ---------------- Kernel A (R5): per-block LDS accumulation, k-major transposed partial writes
__global__ __launch_bounds__(256) void partials(
    const float*  __restrict__ pred_beta,
    const float*  __restrict__ pred_energy,
    const float2* __restrict__ pred_pos,
    const float*  __restrict__ pred_time,
    const float2* __restrict__ pred_id2,
    const float*  __restrict__ t_energy,
    const float2* __restrict__ t_pos,
    const float*  __restrict__ t_time,
    const int*    __restrict__ t_idx,
    u64*    __restrict__ pk_part,   // [K][B1]
    float*  __restrict__ cnt_part,  // [K][B1]
    float*  __restrict__ den_part,  // [K][B1]
    float4* __restrict__ num_part,  // [K][B1]
    float*  __restrict__ noise_part,// [B1]
    int n)
{
    __shared__ u64   spk[KOBJ];
    __shared__ float scnt[KOBJ];
    __shared__ float sden[KOBJ], sn0[KOBJ], sn1[KOBJ], sn2[KOBJ], sn3[KOBJ];
    __shared__ float snoise[256];
    int t = threadIdx.x;
    int b = blockIdx.x;
    spk[t] = 0; scnt[t] = 0.f; sden[t] = 0.f;
    sn0[t] = 0.f; sn1[t] = 0.f; sn2[t] = 0.f; sn3[t] = 0.f;
    __syncthreads();

    float noise = 0.0f;
    for (int i = b * 256 + t; i < n; i += B1 * 256) {
        int tid = t_idx[i];
        float braw = pred_beta[i];
        float beta = fminf(fmaxf(braw, 0.0f), BETA_CLIP_C);
        if (tid >= 0) {
            atomicAdd(&scnt[tid], 1.0f);
            u64 key = ((u64)__float_as_uint(beta) << 32) |
                      (u64)(0x7FFFFFFFu - (unsigned)i);   // max beta, tie -> lowest index
            atomicMax(&spk[tid], key);
            float te = t_energy[i];
            float ew = (te > 10.0f) ? 1.0f : fmaxf(0.0f, (te - 0.5f) / 9.5f);
            float de = te - pred_energy[i];
            float el = de * de / (te + 1.0f);
            float2 tp = t_pos[i];
            float2 pp = pred_pos[i];
            float dpx = tp.x - pp.x, dpy = tp.y - pp.y;
            float pl = (dpx * dpx + dpy * dpy) * 0.01f;
            float dt = t_time[i] - pred_time[i];
            float tl = dt * dt;
            float2 id0 = pred_id2[3 * i];
            float2 id1 = pred_id2[3 * i + 1];
            float2 id2 = pred_id2[3 * i + 2];
            float cs = id0.x * id0.x + id0.y * id0.y + id1.x * id1.x +
                       id1.y * id1.y + id2.x * id2.x + id2.y * id2.y;
            cs *= (1e-8f / 6.0f);
            float mask = (braw < 0.1f) ? 0.0f : 1.0f;  // PAYLOAD_BETA_CLIP on raw beta
            float w = mask * ew * beta;
            atomicAdd(&sden[tid], beta);
            atomicAdd(&sn0[tid], el * w);
            atomicAdd(&sn1[tid], pl * w);
            atomicAdd(&sn2[tid], tl * w);
            atomicAdd(&sn3[tid], cs * w);
        } else {
            noise += beta;
        }
    }
    __syncthreads();
    int o = t * B1 + b;
    pk_part[o]  = spk[t];
    cnt_part[o] = scnt[t];
    den_part[o] = sden[t];
    num_part[o] = make_float4(sn0[t], sn1[t], sn2[t], sn3[t]);
    snoise[t] = noise;
    __syncthreads();
    for (int s = 128; s > 0; s >>= 1) {
        if (t < s) snoise[t] += snoise[t + s];
        __syncthreads();
    }
    if (t == 0) noise_part[b] = snoise[0];
}

// ---------------- Kernel B (R5): one block per object; coalesced row reduce
__global__ __launch_bounds__(256) void merge(
    const float2* __restrict__ pred_ccoords,
    const u64*    __restrict__ pk_part,
    const float*  __restrict__ cnt_part,
    const float*  __restrict__ den_part,
    const float4* __restrict__ num_part,
    float4* __restrict__ objA,   // (xk, yk, qa, cnt)
    float4* __restrict__ objB)   // (pay, lb, valid, 0)
{
    __shared__ u64   spk[256];
    __shared__ float scnt[256], sden[256], snum[256];
    int k = blockIdx.x;
    int b = threadIdx.x;
    int o = k * B1 + b;
    u64 pk = pk_part[o];
    float cnt = cnt_part[o];
    float den = den_part[o];
    float4 v = num_part[o];
    float nsum = v.x + v.y + v.z + v.w;
    spk[b] = pk; scnt[b] = cnt; sden[b] = den; snum[b] = nsum;
    __syncthreads();
    for (int s = 128; s > 0; s >>= 1) {
        if (b < s) {
            u64 p = spk[b + s]; if (p > spk[b]) spk[b] = p;
            scnt[b] += scnt[b + s];
            sden[b] += sden[b + s];
            snum[b] += snum[b + s];
        }
        __syncthreads();
    }
    if (b == 0) {
        float cs = scnt[0];
        bool valid = cs > 0.f;
        float xk = 0.f, yk = 0.f, qa = 0.f, lb = 0.f, pay = 0.f;
        if (valid) {
            u64 p = spk[0];
            unsigned a = 0x7FFFFFFFu - (unsigned)(p & 0xFFFFFFFFull);
            float ba = __uint_as_float((unsigned)(p >> 32));
            float2 cc = pred_ccoords[a];
            xk = cc.x; yk = cc.y;
            float at = atanhf(ba);
            qa = at * at + QMIN;
            lb = 1.0f - ba;
            pay = snum[0] / fmaxf(sden[0], 1e-6f);
        }
        objA[k] = make_float4(xk, yk, qa, cs);
        objB[k] = make_float4(pay, lb, valid ? 1.f : 0.f, 0.f);
    }
}

// ---------------- Kernel C: N x K hinge/attraction, 4 k per lane.
// Block = 256 thr = 4 waves; each wave handles its own 64-point sub-chunk vs ALL 256 k
// (lane l owns k = ki*64+l, ki=0..3). One ds_read_b128 feeds 256 pairs (4x fewer LDS
// instrs than 1-k/thread). 4 wave-partials per (k,block) are transposed through LDS and
// stored as one coalesced float4 per k.
__global__ __launch_bounds__(256) void heavy(
    const float*  __restrict__ pred_beta,
    const float2* __restrict__ pred_ccoords,
    const int*    __restrict__ t_idx,
    const float4* __restrict__ objA,
    float4* __restrict__ rep4,   // [K][hstr] float4 (4 wave-partials)
    float4* __restrict__ att4,   // [K][hstr]
    int n, int hstr)
{
    __shared__ float4 pts[256];
    __shared__ float sred[2][4][256];   // [rep|att][wave][k] = 8 KB
    int t = threadIdx.x;
    int l = t & 63, w = t >> 6;
    int p = blockIdx.x * 256 + t;
    float4 pt;
    if (p < n) {
        float beta = fminf(fmaxf(pred_beta[p], 0.0f), BETA_CLIP_C);
        float at = atanhf(beta);
        float2 cc = pred_ccoords[p];
        pt = make_float4(cc.x, cc.y, at * at + QMIN, __int_as_float(t_idx[p]));
    } else {
        pt = make_float4(0.f, 0.f, 0.f, __int_as_float(-2));  // q=0 => inert
    }
    pts[t] = pt;
    float xk[4], yk[4];
    #pragma unroll
    for (int ki = 0; ki < 4; ++ki) {
        float4 oa = objA[ki * 64 + l];
        xk[ki] = oa.x; yk[ki] = oa.y;
    }
    __syncthreads();
    float rep[4] = {0.f, 0.f, 0.f, 0.f};
    float att[4] = {0.f, 0.f, 0.f, 0.f};
    const int base = w * 64;
    #pragma unroll 4
    for (int j = 0; j < 64; ++j) {
        float4 s = pts[base + j];
        #pragma unroll
        for (int ki = 0; ki < 4; ++ki) {
            float dx = s.x - xk[ki], dy = s.y - yk[ki];
            float d2 = fmaf(dx, dx, dy * dy);
            float r = __builtin_amdgcn_sqrtf(d2 + 1e-6f);
            float h = fmaxf(0.0f, 1.0f - r);
            bool own = (__float_as_int(s.w) == ki * 64 + l);
            rep[ki] = fmaf(own ? 0.0f : h,  s.z, rep[ki]);
            att[ki] = fmaf(own ? d2 : 0.0f, s.z, att[ki]);
        }
    }
    #pragma unroll
    for (int ki = 0; ki < 4; ++ki) {
        sred[0][w][ki * 64 + l] = rep[ki];   // stride-1 across lanes: conflict-free
        sred[1][w][ki * 64 + l] = att[ki];
    }
    __syncthreads();
    // thread t <-> k = t: gather the 4 wave-partials, one float4 store per array
    float4 r4 = make_float4(sred[0][0][t], sred[0][1][t], sred[0][2][t], sred[0][3][t]);
    float4 a4 = make_float4(sred[1][0][t], sred[1][1][t], sred[1][2][t], sred[1][3][t]);
    int o = t * hstr + blockIdx.x;
    rep4[o] = r4;
    att4[o] = a4;
}

// ---------------- Kernel D1: per-object reduce of heavy partials (coalesced float4 rows)
__global__ __launch_bounds__(256) void final1(
    const float4* __restrict__ objA,
    const float4* __restrict__ objB,
    const float4* __restrict__ rep4,
    const float4* __restrict__ att4,
    float4* __restrict__ objC,   // (s0, valid, cnt, 0)
    int n, int nbh, int hstr)
{
    __shared__ float srep[256], satt[256];
    int k = blockIdx.x;
    int b = threadIdx.x;
    float rep = 0.f, att = 0.f;
    for (int c = b; c < nbh; c += 256) {
        float4 r = rep4[k * hstr + c];
        float4 a = att4[k * hstr + c];
        rep += r.x + r.y + r.z + r.w;
        att += a.x + a.y + a.z + a.w;
    }
    srep[b] = rep; satt[b] = att;
    __syncthreads();
    for (int s = 128; s > 0; s >>= 1) {
        if (b < s) { srep[b] += srep[b + s]; satt[b] += satt[b + s]; }
        __syncthreads();
    }
    if (b == 0) {
        float4 a  = objA[k];
        float4 b4 = objB[k];
        float cnt = a.w, qa = a.z, valid = b4.z;
        float vatt = valid * satt[0] * qa / fmaxf(cnt, 1.0f);
        float vrep = valid * srep[0] * qa / fmaxf((float)n - cnt, 1.0f);
        objC[k] = make_float4(vatt + vrep + b4.y + b4.x, valid, cnt, 0.f);
    }
}

// ---------------- Kernel D2 (R5): scalar finish
__global__ __launch_bounds__(256) void final2(
    const float4* __restrict__ objC,
    const float*  __restrict__ noise_part,
    float* __restrict__ out, int n)
{
    __shared__ float4 sred[256];
    int t = threadIdx.x;
    float4 c = objC[t];
    c.w = noise_part[t];
    sred[t] = c;
    __syncthreads();
    for (int s = 128; s > 0; s >>= 1) {
        if (t < s) {
            float4 x = sred[t], y = sred[t + s];
            sred[t] = make_float4(x.x + y.x, x.y + y.y, x.z + y.z, x.w + y.w);
        }
        __syncthreads();
    }
    if (t == 0) {
        float4 r = sred[0];
        float nv = fmaxf(r.y, 1.0f);                    // n_valid
        float nnoise = fmaxf((float)n - r.z, 1.0f);     // noise count
        out[0] = r.x / nv + r.w / nnoise;
    }
}

extern "C" void kernel_launch(void* const* d_in, const int* in_sizes, int n_in,
                              void* d_out, int out_size, void* d_ws, size_t ws_size,
                              hipStream_t stream) {
    const float*  pred_beta    = (const float*)d_in[0];
    const float2* pred_ccoords = (const float2*)d_in[1];
    const float*  pred_energy  = (const float*)d_in[2];
    const float2* pred_pos     = (const float2*)d_in[3];
    const float*  pred_time    = (const float*)d_in[4];
    const float2* pred_id2     = (const float2*)d_in[5];
    const float*  t_energy     = (const float*)d_in[6];
    const float2* t_pos        = (const float2*)d_in[7];
    const float*  t_time       = (const float*)d_in[8];
    const int*    t_idx        = (const int*)d_in[10];
    int n = in_sizes[0];
    int nbh = (n + 255) / 256;          // 391 for n=100000
    int hstr = (nbh + 8) & ~7;          // padded float4-row stride (392)

    // workspace carve (16B-aligned)
    char* base = (char*)d_ws;
    size_t off = 0;
    u64*    pk_part    = (u64*)   (base + off); off += (size_t)KOBJ * B1 * 8;    // 512 KB
    float*  cnt_part   = (float*) (base + off); off += (size_t)KOBJ * B1 * 4;    // 256 KB
    float*  den_part   = (float*) (base + off); off += (size_t)KOBJ * B1 * 4;    // 256 KB
    float4* num_part   = (float4*)(base + off); off += (size_t)KOBJ * B1 * 16;   // 1 MB
    float*  noise_part = (float*) (base + off); off += 256 * 4;
    float4* objA       = (float4*)(base + off); off += KOBJ * 16;
    float4* objB       = (float4*)(base + off); off += KOBJ * 16;
    float4* objC       = (float4*)(base + off); off += KOBJ * 16;
    float4* rep4       = (float4*)(base + off); off += (size_t)KOBJ * hstr * 16; // 1.6 MB
    float4* att4       = (float4*)(base + off); off += (size_t)KOBJ * hstr * 16; // 1.6 MB

    partials<<<B1, 256, 0, stream>>>(pred_beta, pred_energy, pred_pos, pred_time,
                                     pred_id2, t_energy, t_pos, t_time, t_idx,
                                     pk_part, cnt_part, den_part, num_part, noise_part, n);
    merge<<<KOBJ, 256, 0, stream>>>(pred_ccoords, pk_part, cnt_part, den_part, num_part,
                                    objA, objB);
    heavy<<<nbh, 256, 0, stream>>>(pred_beta, pred_ccoords, t_idx, objA,
                                   rep4, att4, n, hstr);
    final1<<<KOBJ, 256, 0, stream>>>(objA, objB, rep4, att4, objC, n, nbh, hstr);
    final2<<<1, 256, 0, stream>>>(objC, noise_part, (float*)d_out, n);
}

// Round 8
// 106.219 us; speedup vs baseline: 1.2930x; 1.0419x over previous
//
#include <hip/hip_runtime.h>
#include <hip/hip_bf16.h>
#include <math.h>

#define KOBJ 256
#define B1   256              // partial-accumulator blocks
#define QMIN 0.5f
#define BETA_CLIP_C (1.0f - 1e-5f)

typedef unsigned long long u64;

// ---------------- Kernel A: per-block LDS accumulation, k-major transposed partial writes.
// num accumulators collapsed 4 -> 1: sum payload components before accumulation
// (Sum_c num_c / den == (Sum_c num_c)/den, exact algebra).
__global__ __launch_bounds__(256) void partials(
    const float*  __restrict__ pred_beta,
    const float*  __restrict__ pred_energy,
    const float2* __restrict__ pred_pos,
    const float*  __restrict__ pred_time,
    const float2* __restrict__ pred_id2,
    const float*  __restrict__ t_energy,
    const float2* __restrict__ t_pos,
    const float*  __restrict__ t_time,
    const int*    __restrict__ t_idx,
    u64*    __restrict__ pk_part,   // [K][B1]
    float*  __restrict__ cnt_part,  // [K][B1]
    float*  __restrict__ den_part,  // [K][B1]
    float*  __restrict__ num_part,  // [K][B1]
    float*  __restrict__ noise_part,// [B1]
    int n)
{
    __shared__ u64   spk[KOBJ];
    __shared__ float scnt[KOBJ];
    __shared__ float sden[KOBJ], snum[KOBJ];
    __shared__ float snoise[256];
    int t = threadIdx.x;
    int b = blockIdx.x;
    spk[t] = 0; scnt[t] = 0.f; sden[t] = 0.f; snum[t] = 0.f;
    __syncthreads();

    float noise = 0.0f;
    for (int i = b * 256 + t; i < n; i += B1 * 256) {
        int tid = t_idx[i];
        float braw = pred_beta[i];
        float beta = fminf(fmaxf(braw, 0.0f), BETA_CLIP_C);
        if (tid >= 0) {
            atomicAdd(&scnt[tid], 1.0f);
            u64 key = ((u64)__float_as_uint(beta) << 32) |
                      (u64)(0x7FFFFFFFu - (unsigned)i);   // max beta, tie -> lowest index
            atomicMax(&spk[tid], key);
            float te = t_energy[i];
            float ew = (te > 10.0f) ? 1.0f : fmaxf(0.0f, (te - 0.5f) / 9.5f);
            float de = te - pred_energy[i];
            float el = de * de / (te + 1.0f);
            float2 tp = t_pos[i];
            float2 pp = pred_pos[i];
            float dpx = tp.x - pp.x, dpy = tp.y - pp.y;
            float pl = (dpx * dpx + dpy * dpy) * 0.01f;
            float dt = t_time[i] - pred_time[i];
            float tl = dt * dt;
            float2 id0 = pred_id2[3 * i];
            float2 id1 = pred_id2[3 * i + 1];
            float2 id2 = pred_id2[3 * i + 2];
            float cs = id0.x * id0.x + id0.y * id0.y + id1.x * id1.x +
                       id1.y * id1.y + id2.x * id2.x + id2.y * id2.y;
            cs *= (1e-8f / 6.0f);
            float mask = (braw < 0.1f) ? 0.0f : 1.0f;  // PAYLOAD_BETA_CLIP on raw beta
            float w = mask * ew * beta;
            atomicAdd(&sden[tid], beta);
            atomicAdd(&snum[tid], (el + pl + tl + cs) * w);
        } else {
            noise += beta;
        }
    }
    __syncthreads();
    int o = t * B1 + b;
    pk_part[o]  = spk[t];
    cnt_part[o] = scnt[t];
    den_part[o] = sden[t];
    num_part[o] = snum[t];
    snoise[t] = noise;
    __syncthreads();
    for (int s = 128; s > 0; s >>= 1) {
        if (t < s) snoise[t] += snoise[t + s];
        __syncthreads();
    }
    if (t == 0) noise_part[b] = snoise[0];
}

// ---------------- Kernel B: one block per object; coalesced row reduce
__global__ __launch_bounds__(256) void merge(
    const float2* __restrict__ pred_ccoords,
    const u64*    __restrict__ pk_part,
    const float*  __restrict__ cnt_part,
    const float*  __restrict__ den_part,
    const float*  __restrict__ num_part,
    float4* __restrict__ objA,   // (xk, yk, qa, cnt)
    float4* __restrict__ objB)   // (pay, lb, valid, 0)
{
    __shared__ u64   spk[256];
    __shared__ float scnt[256], sden[256], snum[256];
    int k = blockIdx.x;
    int b = threadIdx.x;
    int o = k * B1 + b;
    u64 pk = pk_part[o];
    float cnt = cnt_part[o];
    float den = den_part[o];
    float nsum = num_part[o];
    spk[b] = pk; scnt[b] = cnt; sden[b] = den; snum[b] = nsum;
    __syncthreads();
    for (int s = 128; s > 0; s >>= 1) {
        if (b < s) {
            u64 p = spk[b + s]; if (p > spk[b]) spk[b] = p;
            scnt[b] += scnt[b + s];
            sden[b] += sden[b + s];
            snum[b] += snum[b + s];
        }
        __syncthreads();
    }
    if (b == 0) {
        float cs = scnt[0];
        bool valid = cs > 0.f;
        float xk = 0.f, yk = 0.f, qa = 0.f, lb = 0.f, pay = 0.f;
        if (valid) {
            u64 p = spk[0];
            unsigned a = 0x7FFFFFFFu - (unsigned)(p & 0xFFFFFFFFull);
            float ba = __uint_as_float((unsigned)(p >> 32));
            float2 cc = pred_ccoords[a];
            xk = cc.x; yk = cc.y;
            float at = atanhf(ba);
            qa = at * at + QMIN;
            lb = 1.0f - ba;
            pay = snum[0] / fmaxf(sden[0], 1e-6f);
        }
        objA[k] = make_float4(xk, yk, qa, cs);
        objB[k] = make_float4(pay, lb, valid ? 1.f : 0.f, 0.f);
    }
}

// ---------------- Kernel C (R5-proven): N x K hinge/attraction; k-major partial writes
__global__ __launch_bounds__(256) void heavy(
    const float*  __restrict__ pred_beta,
    const float2* __restrict__ pred_ccoords,
    const int*    __restrict__ t_idx,
    const float4* __restrict__ objA,
    float* __restrict__ rep_part,   // [K][hstr]
    float* __restrict__ att_part,   // [K][hstr]
    int n, int hstr)
{
    __shared__ float4 pts[256];
    int t = threadIdx.x;
    int p = blockIdx.x * 256 + t;
    float4 pt;
    if (p < n) {
        float beta = fminf(fmaxf(pred_beta[p], 0.0f), BETA_CLIP_C);
        float at = atanhf(beta);
        float2 cc = pred_ccoords[p];
        pt = make_float4(cc.x, cc.y, at * at + QMIN, __int_as_float(t_idx[p]));
    } else {
        pt = make_float4(0.f, 0.f, 0.f, __int_as_float(-2));  // q=0 => inert
    }
    pts[t] = pt;
    float4 oa = objA[t];
    float xk = oa.x, yk = oa.y;
    __syncthreads();
    float rep = 0.f, att = 0.f;
    #pragma unroll 8
    for (int j = 0; j < 256; ++j) {
        float4 s = pts[j];                    // wave-uniform address -> bank broadcast
        float dx = s.x - xk, dy = s.y - yk;
        float d2 = fmaf(dx, dx, dy * dy);
        float r = __builtin_amdgcn_sqrtf(d2 + 1e-6f);
        float h = fmaxf(0.0f, 1.0f - r);
        bool own = (__float_as_int(s.w) == t);
        rep = fmaf(own ? 0.0f : h,  s.z, rep);
        att = fmaf(own ? d2 : 0.0f, s.z, att);
    }
    int o = t * hstr + blockIdx.x;
    rep_part[o] = rep;
    att_part[o] = att;
}

// ---------------- Kernel D1: per-object reduce of heavy partials (coalesced rows)
__global__ __launch_bounds__(256) void final1(
    const float4* __restrict__ objA,
    const float4* __restrict__ objB,
    const float*  __restrict__ rep_part,
    const float*  __restrict__ att_part,
    float4* __restrict__ objC,   // (s0, valid, cnt, 0)
    int n, int nbh, int hstr)
{
    __shared__ float srep[256], satt[256];
    int k = blockIdx.x;
    int b = threadIdx.x;
    float rep = 0.f, att = 0.f;
    int o = k * hstr + b;
    if (b < nbh)        { rep += rep_part[o];        att += att_part[o]; }
    if (b + 256 < nbh)  { rep += rep_part[o + 256];  att += att_part[o + 256]; }
    srep[b] = rep; satt[b] = att;
    __syncthreads();
    for (int s = 128; s > 0; s >>= 1) {
        if (b < s) { srep[b] += srep[b + s]; satt[b] += satt[b + s]; }
        __syncthreads();
    }
    if (b == 0) {
        float4 a  = objA[k];
        float4 b4 = objB[k];
        float cnt = a.w, qa = a.z, valid = b4.z;
        float vatt = valid * satt[0] * qa / fmaxf(cnt, 1.0f);
        float vrep = valid * srep[0] * qa / fmaxf((float)n - cnt, 1.0f);
        objC[k] = make_float4(vatt + vrep + b4.y + b4.x, valid, cnt, 0.f);
    }
}

// ---------------- Kernel D2: scalar finish
__global__ __launch_bounds__(256) void final2(
    const float4* __restrict__ objC,
    const float*  __restrict__ noise_part,
    float* __restrict__ out, int n)
{
    __shared__ float4 sred[256];
    int t = threadIdx.x;
    float4 c = objC[t];
    c.w = noise_part[t];
    sred[t] = c;
    __syncthreads();
    for (int s = 128; s > 0; s >>= 1) {
        if (t < s) {
            float4 x = sred[t], y = sred[t + s];
            sred[t] = make_float4(x.x + y.x, x.y + y.y, x.z + y.z, x.w + y.w);
        }
        __syncthreads();
    }
    if (t == 0) {
        float4 r = sred[0];
        float nv = fmaxf(r.y, 1.0f);                    // n_valid
        float nnoise = fmaxf((float)n - r.z, 1.0f);     // noise count
        out[0] = r.x / nv + r.w / nnoise;
    }
}

extern "C" void kernel_launch(void* const* d_in, const int* in_sizes, int n_in,
                              void* d_out, int out_size, void* d_ws, size_t ws_size,
                              hipStream_t stream) {
    const float*  pred_beta    = (const float*)d_in[0];
    const float2* pred_ccoords = (const float2*)d_in[1];
    const float*  pred_energy  = (const float*)d_in[2];
    const float2* pred_pos     = (const float2*)d_in[3];
    const float*  pred_time    = (const float*)d_in[4];
    const float2* pred_id2     = (const float2*)d_in[5];
    const float*  t_energy     = (const float*)d_in[6];
    const float2* t_pos        = (const float2*)d_in[7];
    const float*  t_time       = (const float*)d_in[8];
    const int*    t_idx        = (const int*)d_in[10];
    int n = in_sizes[0];
    int nbh = (n + 255) / 256;          // 391 for n=100000
    int hstr = (nbh + 8) & ~7;          // padded row stride (392)

    // workspace carve (16B-aligned)
    char* base = (char*)d_ws;
    size_t off = 0;
    u64*    pk_part    = (u64*)   (base + off); off += (size_t)KOBJ * B1 * 8;    // 512 KB
    float*  cnt_part   = (float*) (base + off); off += (size_t)KOBJ * B1 * 4;    // 256 KB
    float*  den_part   = (float*) (base + off); off += (size_t)KOBJ * B1 * 4;    // 256 KB
    float*  num_part   = (float*) (base + off); off += (size_t)KOBJ * B1 * 4;    // 256 KB
    float*  noise_part = (float*) (base + off); off += 256 * 4;
    float4* objA       = (float4*)(base + off); off += KOBJ * 16;
    float4* objB       = (float4*)(base + off); off += KOBJ * 16;
    float4* objC       = (float4*)(base + off); off += KOBJ * 16;
    float*  rep_part   = (float*) (base + off); off += (size_t)KOBJ * hstr * 4;  // ~400 KB
    float*  att_part   = (float*) (base + off); off += (size_t)KOBJ * hstr * 4;

    partials<<<B1, 256, 0, stream>>>(pred_beta, pred_energy, pred_pos, pred_time,
                                     pred_id2, t_energy, t_pos, t_time, t_idx,
                                     pk_part, cnt_part, den_part, num_part, noise_part, n);
    merge<<<KOBJ, 256, 0, stream>>>(pred_ccoords, pk_part, cnt_part, den_part, num_part,
                                    objA, objB);
    heavy<<<nbh, 256, 0, stream>>>(pred_beta, pred_ccoords, t_idx, objA,
                                   rep_part, att_part, n, hstr);
    final1<<<KOBJ, 256, 0, stream>>>(objA, objB, rep_part, att_part, objC, n, nbh, hstr);
    final2<<<1, 256, 0, stream>>>(objC, noise_part, (float*)d_out, n);
}